// Round 7
// baseline (223.190 us; speedup 1.0000x reference)
//
#include <hip/hip_runtime.h>
#include <hip/hip_bf16.h>

typedef __bf16 bf16;
typedef bf16 bf16x8 __attribute__((ext_vector_type(8)));
typedef bf16 bf16x4 __attribute__((ext_vector_type(4)));
typedef float f32x4 __attribute__((ext_vector_type(4)));

#define Bn 8
#define Cdim 256
#define Nn 2304
#define NH 4
#define DH 32
#define HID 128
#define QSCALE (0.17677669529663687f * 1.4426950408889634f)
#define SMAX 14.0f
#define QSZ ((size_t)32 * Nn * DH)
#define WQ_ELEMS (3 * HID * Cdim)
#define WO_ELEMS (Cdim * HID)

// ---------------- Kernel 0: weight cvt + FRAG-MAJOR repack (gather) ----------
__global__ __launch_bounds__(256) void cvt_kernel(const float* __restrict__ wq,
                                                  const float* __restrict__ wo,
                                                  bf16* __restrict__ dst) {
    int d = blockIdx.x * 256 + threadIdx.x;
    {   // wq: 24 o-tiles, 8 kc
        int j = d & 7, lane = (d >> 3) & 63, kc = (d >> 9) & 7, ot = d >> 12;
        int o = ot * 16 + (lane & 15), c = kc * 32 + (lane >> 4) * 8 + j;
        dst[d] = (bf16)wq[o * Cdim + c];
    }
    if (d < WO_ELEMS) {   // wo: 16 o-tiles, 4 kc
        int j = d & 7, lane = (d >> 3) & 63, kc = (d >> 9) & 3, ot = d >> 11;
        int o = ot * 16 + (lane & 15), c = kc * 32 + (lane >> 4) * 8 + j;
        dst[WQ_ELEMS + d] = (bf16)wo[o * HID + c];
    }
}

// ---------------- Kernel 1: QKV projection (LDS-staged x, 4-way o-split) -----
__global__ __launch_bounds__(256) void qkv_kernel(const float* __restrict__ x,
                                                  const bf16* __restrict__ w,
                                                  bf16* __restrict__ ws) {
    __shared__ alignas(16) float xs[256 * 16];   // [ch][px] 16 KB
    const int b   = blockIdx.y;
    const int tid = threadIdx.x;
    const int lane = tid & 63, w4 = tid >> 6, l16 = lane & 15, quad = lane >> 4;
    const int p0  = blockIdx.x * 16;
    const float* xb = x + (size_t)b * Cdim * Nn + p0;

    // stage: wave w4 covers channels [w4*64, +64); lane covers 1 ch x 4 px
    #pragma unroll
    for (int k = 0; k < 4; ++k) {
        const int ch = w4 * 64 + k * 16 + (lane >> 2);
        const int px = (lane & 3) * 4;
        const float4 v = *(const float4*)&xb[(size_t)ch * Nn + px];
        *(float4*)&xs[ch * 16 + px] = v;
    }
    __syncthreads();

    bf16x8 bx[8];
    #pragma unroll
    for (int kc = 0; kc < 8; ++kc)
        #pragma unroll
        for (int jj = 0; jj < 8; ++jj)
            bx[kc][jj] = (bf16)xs[(kc * 32 + quad * 8 + jj) * 16 + l16];

    const int p = p0 + l16;
    #pragma unroll 1
    for (int oi = 0; oi < 6; ++oi) {
        const int ot = w4 * 6 + oi;
        f32x4 acc0 = {0.f, 0.f, 0.f, 0.f};
        f32x4 acc1 = {0.f, 0.f, 0.f, 0.f};
        #pragma unroll
        for (int kc = 0; kc < 4; ++kc) {
            bf16x8 aw0 = *(const bf16x8*)&w[(((size_t)ot * 8 + kc) * 64 + lane) * 8];
            bf16x8 aw1 = *(const bf16x8*)&w[(((size_t)ot * 8 + kc + 4) * 64 + lane) * 8];
            acc0 = __builtin_amdgcn_mfma_f32_16x16x32_bf16(aw0, bx[kc],     acc0, 0, 0, 0);
            acc1 = __builtin_amdgcn_mfma_f32_16x16x32_bf16(aw1, bx[kc + 4], acc1, 0, 0, 0);
        }
        const int obase = ot * 16 + quad * 4;
        const int t     = obase >> 7;
        const int rem   = obase & 127;
        const int h     = rem >> 5;
        const int dbase = rem & 31;
        if (t == 2) {
            // V frag-major: elem (d, n=p) at (n>>5)*1024 + (d>>4)*512
            //   + ((n>>3)&3)*128 + (d&15)*8 + (n&7)
            bf16* vf = ws + 2 * QSZ + (size_t)(b * NH + h) * DH * Nn;
            const int vb_ = (p >> 5) * 1024 + ((p >> 3) & 3) * 128 + (p & 7);
            #pragma unroll
            for (int r = 0; r < 4; ++r) {
                const int d = dbase + r;
                vf[vb_ + (d >> 4) * 512 + (d & 15) * 8] = (bf16)(acc0[r] + acc1[r]);
            }
        } else if (t == 1) {
            bf16x4 v4;
            #pragma unroll
            for (int r = 0; r < 4; ++r) v4[r] = (bf16)(acc0[r] + acc1[r]);
            bf16* kf = ws + QSZ + (size_t)(b * NH + h) * Nn * DH;
            const int pp   = p & 31;
            const int tt   = (pp >> 2) & 1;
            const int rho  = ((pp >> 3) << 2) | (pp & 3);
            const int addr = (((p >> 5) * 2 + tt) * 64 + (dbase >> 3) * 16 + rho) * 8 + (dbase & 7);
            *(bf16x4*)&kf[addr] = v4;
        } else {
            bf16x4 v4;
            #pragma unroll
            for (int r = 0; r < 4; ++r) v4[r] = (bf16)((acc0[r] + acc1[r]) * QSCALE);
            size_t addr = ((size_t)(b * NH + h) * Nn + p) * DH + dbase;
            *(bf16x4*)&ws[addr] = v4;
        }
    }
}

// ---------------- Kernel 2: flash attention, lean 168-VGPR tier --------------
// 64 Q-rows/WG, wave w owns j-quarter; reg-P via permuted-K. Register-tier
// history: (256,3)+loose structure -> compiler squeezed to 64 VGPR, serialized
// loads (r1, 47us); (256,2)+K/V dbuf -> ~200 VGPR, 2 waves/SIMD (r3, ~39us);
// (256,4) 128-cap -> 224B/thread spill (r4, 83us). This version targets the
// untried middle: intrinsic demand ~146 under the (256,3) 168 cap for 3
// waves/SIMD. Shaves vs r3: ones-MFMA row-sum -> VALU lp + 2 shfl_xor
// (-16 VGPR, -72 MFMA); QK s-tiles processed 2-at-a-time (halves live exp2
// temps, -12); V single-buffered JIT at cc-top (first use ~150cy later,
// behind s0/s1+exp2). K keeps the pinned register double-buffer.
__global__ __launch_bounds__(256, 3) void attn_kernel(bf16* __restrict__ ws) {
    __shared__ alignas(16) float smem[4 * 64 * 17 + 4 * 64];   // 18432 B
    const int g   = blockIdx.x;
    const int grp = g >> 3;
    const int bh  = (g & 7) * 4 + grp / 36;
    const int i0  = (grp % 36) * 64;
    const int tid = threadIdx.x;
    const int lane = tid & 63, w4 = tid >> 6, l16 = lane & 15, quad = lane >> 4;
    const int jbase = w4 * 576;

    const bf16* Qb = ws + (size_t)bh * Nn * DH;
    const bf16* Kf = ws + QSZ + (size_t)bh * Nn * DH;       // permuted frag-major
    const bf16* Vf = ws + 2 * QSZ + (size_t)bh * DH * Nn;   // frag-major A-operand

    bf16x8 aq[4];
    #pragma unroll
    for (int it = 0; it < 4; ++it)
        aq[it] = *(const bf16x8*)&Qb[(size_t)(i0 + it * 16 + l16) * DH + quad * 8];

    f32x4 o[4][2];
    float lp[4] = {0.f, 0.f, 0.f, 0.f};
    #pragma unroll
    for (int it = 0; it < 4; ++it) {
        o[it][0] = {0.f, 0.f, 0.f, 0.f};
        o[it][1] = {0.f, 0.f, 0.f, 0.f};
    }
    const f32x4 negM = {-SMAX, -SMAX, -SMAX, -SMAX};

    bf16x8 ka[4], kb[4];
    {   // prologue: K for cc = 0
        const bf16* kp = &Kf[(size_t)(jbase >> 4) * 512 + lane * 8];
        #pragma unroll
        for (int jt = 0; jt < 4; ++jt) ka[jt] = *(const bf16x8*)&kp[jt * 512];
    }

    auto body = [&](int cc, const bf16x8 (&kc)[4], bf16x8 (&kn)[4], bool pref) {
        const int j0 = jbase + cc * 64;
        const bf16* vp = &Vf[(size_t)(j0 >> 5) * 1024 + lane * 8];
        bf16x8 vv0 = *(const bf16x8*)&vp[0];
        bf16x8 vv1 = *(const bf16x8*)&vp[1024];
        bf16x8 vv2 = *(const bf16x8*)&vp[512];
        bf16x8 vv3 = *(const bf16x8*)&vp[1536];
        if (pref) {   // issue next-cc K; pinned so it can't be sunk
            const bf16* kp = &Kf[(size_t)((j0 + 64) >> 4) * 512 + lane * 8];
            #pragma unroll
            for (int jt = 0; jt < 4; ++jt) kn[jt] = *(const bf16x8*)&kp[jt * 512];
            __builtin_amdgcn_sched_barrier(0);
        }
        #pragma unroll
        for (int it = 0; it < 4; ++it) {
            // ---- first half: tiles 0,1 -> pf -> 2 PV MFMAs ----
            {
                f32x4 s0 = __builtin_amdgcn_mfma_f32_16x16x32_bf16(kc[0], aq[it], negM, 0, 0, 0);
                f32x4 s1 = __builtin_amdgcn_mfma_f32_16x16x32_bf16(kc[1], aq[it], negM, 0, 0, 0);
                float e0 = __builtin_amdgcn_exp2f(s0[0]), e1 = __builtin_amdgcn_exp2f(s0[1]);
                float e2 = __builtin_amdgcn_exp2f(s0[2]), e3 = __builtin_amdgcn_exp2f(s0[3]);
                float e4 = __builtin_amdgcn_exp2f(s1[0]), e5 = __builtin_amdgcn_exp2f(s1[1]);
                float e6 = __builtin_amdgcn_exp2f(s1[2]), e7 = __builtin_amdgcn_exp2f(s1[3]);
                lp[it] += ((e0 + e1) + (e2 + e3)) + ((e4 + e5) + (e6 + e7));
                bf16x8 pf;
                pf[0] = (bf16)e0; pf[1] = (bf16)e1; pf[2] = (bf16)e2; pf[3] = (bf16)e3;
                pf[4] = (bf16)e4; pf[5] = (bf16)e5; pf[6] = (bf16)e6; pf[7] = (bf16)e7;
                o[it][0] = __builtin_amdgcn_mfma_f32_16x16x32_bf16(vv0, pf, o[it][0], 0, 0, 0);
                o[it][1] = __builtin_amdgcn_mfma_f32_16x16x32_bf16(vv2, pf, o[it][1], 0, 0, 0);
            }
            // ---- second half: tiles 2,3 -> pf -> 2 PV MFMAs ----
            {
                f32x4 s2 = __builtin_amdgcn_mfma_f32_16x16x32_bf16(kc[2], aq[it], negM, 0, 0, 0);
                f32x4 s3 = __builtin_amdgcn_mfma_f32_16x16x32_bf16(kc[3], aq[it], negM, 0, 0, 0);
                float e0 = __builtin_amdgcn_exp2f(s2[0]), e1 = __builtin_amdgcn_exp2f(s2[1]);
                float e2 = __builtin_amdgcn_exp2f(s2[2]), e3 = __builtin_amdgcn_exp2f(s2[3]);
                float e4 = __builtin_amdgcn_exp2f(s3[0]), e5 = __builtin_amdgcn_exp2f(s3[1]);
                float e6 = __builtin_amdgcn_exp2f(s3[2]), e7 = __builtin_amdgcn_exp2f(s3[3]);
                lp[it] += ((e0 + e1) + (e2 + e3)) + ((e4 + e5) + (e6 + e7));
                bf16x8 pf;
                pf[0] = (bf16)e0; pf[1] = (bf16)e1; pf[2] = (bf16)e2; pf[3] = (bf16)e3;
                pf[4] = (bf16)e4; pf[5] = (bf16)e5; pf[6] = (bf16)e6; pf[7] = (bf16)e7;
                o[it][0] = __builtin_amdgcn_mfma_f32_16x16x32_bf16(vv1, pf, o[it][0], 0, 0, 0);
                o[it][1] = __builtin_amdgcn_mfma_f32_16x16x32_bf16(vv3, pf, o[it][1], 0, 0, 0);
            }
        }
    };

    #pragma unroll 1
    for (int cp = 0; cp < 4; ++cp) {
        body(cp * 2,     ka, kb, true);
        body(cp * 2 + 1, kb, ka, true);
    }
    body(8, ka, kb, false);

    // cross-quad row-sum finish (lane's lp covers its quad's 16 j per cc)
    float lt[4];
    #pragma unroll
    for (int it = 0; it < 4; ++it) {
        float v = lp[it];
        v += __shfl_xor(v, 16);
        v += __shfl_xor(v, 32);
        lt[it] = v;
    }

    // ---- split-K combine across the 4 waves, two d-halves over one buffer ----
    // lane holds O^T[d = half*16 + quad*4 + r][i = l16]; lt[it] = l for i=l16.
    float* ob = smem;                    // [w][64 rows(i)][17]
    float* lb = smem + 4 * 64 * 17;      // [w][64]
    bf16* Ab = ws + 3 * QSZ + (size_t)(bh >> 2) * ((size_t)Nn * HID);  // frag-major per b
    const int hh = bh & 3;

    #pragma unroll
    for (int it = 0; it < 4; ++it) {
        #pragma unroll
        for (int r = 0; r < 4; ++r)
            ob[(w4 * 64 + it * 16 + l16) * 17 + quad * 4 + r] = o[it][0][r];
        if (quad == 0) lb[w4 * 64 + it * 16 + l16] = lt[it];
    }
    __syncthreads();
    float linv[4];
    #pragma unroll
    for (int k = 0; k < 4; ++k) {
        const int idx = k * 256 + tid;
        const int row = idx >> 4, dd = idx & 15;
        float os = ob[row * 17 + dd] + ob[(64 + row) * 17 + dd]
                 + ob[(128 + row) * 17 + dd] + ob[(192 + row) * 17 + dd];
        float lsum = lb[row] + lb[64 + row] + lb[128 + row] + lb[192 + row];
        linv[k] = 1.0f / lsum;
        const int p = i0 + row;
        Ab[(((size_t)(p >> 4)) * 4 + hh) * 512 + (dd >> 3) * 128 + (p & 15) * 8 + (dd & 7)]
            = (bf16)(os * linv[k]);
    }
    __syncthreads();
    #pragma unroll
    for (int it = 0; it < 4; ++it)
        #pragma unroll
        for (int r = 0; r < 4; ++r)
            ob[(w4 * 64 + it * 16 + l16) * 17 + quad * 4 + r] = o[it][1][r];
    __syncthreads();
    #pragma unroll
    for (int k = 0; k < 4; ++k) {
        const int idx = k * 256 + tid;
        const int row = idx >> 4, dd = idx & 15;
        float os = ob[row * 17 + dd] + ob[(64 + row) * 17 + dd]
                 + ob[(128 + row) * 17 + dd] + ob[(192 + row) * 17 + dd];
        const int p = i0 + row;
        Ab[(((size_t)(p >> 4)) * 4 + hh) * 512 + (2 + (dd >> 3)) * 128 + (p & 15) * 8 + (dd & 7)]
            = (bf16)(os * linv[k]);
    }
}

// ---------------- Kernel 3: output projection (z-split x4, coalesced A) ------
__global__ __launch_bounds__(256) void out_kernel(const bf16* __restrict__ wout,
                                                  const float* __restrict__ bout,
                                                  const bf16* __restrict__ Abuf,
                                                  float* __restrict__ out) {
    const int p0  = blockIdx.x * 64;
    const int b   = blockIdx.y;
    const int otb = blockIdx.z * 4;
    const int tid = threadIdx.x;
    const int lane = tid & 63, w4 = tid >> 6, l16 = lane & 15, quad = lane >> 4;
    const int p = p0 + w4 * 16 + l16;
    const int tile = blockIdx.x * 4 + w4;

    bf16x8 bfrag[4];
    #pragma unroll
    for (int h = 0; h < NH; ++h)
        bfrag[h] = *(const bf16x8*)&Abuf[(((size_t)b * 144 + tile) * 4 + h) * 512 + lane * 8];

    #pragma unroll 1
    for (int oi = 0; oi < 4; ++oi) {
        const int ot = otb + oi;
        const int o0 = ot * 16;
        float4 b4 = *(const float4*)&bout[o0 + quad * 4];
        f32x4 acc0 = {b4.x, b4.y, b4.z, b4.w};
        f32x4 acc1 = {0.f, 0.f, 0.f, 0.f};
        #pragma unroll
        for (int kc = 0; kc < 2; ++kc) {
            bf16x8 aw0 = *(const bf16x8*)&wout[(((size_t)ot * 4 + kc) * 64 + lane) * 8];
            bf16x8 aw1 = *(const bf16x8*)&wout[(((size_t)ot * 4 + kc + 2) * 64 + lane) * 8];
            acc0 = __builtin_amdgcn_mfma_f32_16x16x32_bf16(aw0, bfrag[kc],     acc0, 0, 0, 0);
            acc1 = __builtin_amdgcn_mfma_f32_16x16x32_bf16(aw1, bfrag[kc + 2], acc1, 0, 0, 0);
        }
        #pragma unroll
        for (int r = 0; r < 4; ++r) {
            const int o = o0 + quad * 4 + r;
            out[((size_t)(b * Cdim + o)) * Nn + p] = acc0[r] + acc1[r];
        }
    }
}

extern "C" void kernel_launch(void* const* d_in, const int* in_sizes, int n_in,
                              void* d_out, int out_size, void* d_ws, size_t ws_size,
                              hipStream_t stream) {
    const float* x     = (const float*)d_in[0];
    const float* w_qkv = (const float*)d_in[1];
    const float* w_out = (const float*)d_in[2];
    const float* b_out = (const float*)d_in[3];
    bf16* ws   = (bf16*)d_ws;
    float* out = (float*)d_out;

    bf16* wq_bf = ws + 4 * QSZ;
    bf16* wo_bf = wq_bf + WQ_ELEMS;

    cvt_kernel <<<dim3(WQ_ELEMS / 256), 256, 0, stream>>>(w_qkv, w_out, wq_bf);
    qkv_kernel <<<dim3(144, Bn),   256, 0, stream>>>(x, wq_bf, ws);
    attn_kernel<<<dim3(1152),      256, 0, stream>>>(ws);
    out_kernel <<<dim3(36, Bn, 4), 256, 0, stream>>>(wo_bf, b_out, ws + 3 * QSZ, out);
}

// Round 8
// 126.582 us; speedup vs baseline: 1.7632x; 1.7632x over previous
//
#include <hip/hip_runtime.h>
#include <hip/hip_bf16.h>

typedef __bf16 bf16;
typedef bf16 bf16x8 __attribute__((ext_vector_type(8)));
typedef bf16 bf16x4 __attribute__((ext_vector_type(4)));
typedef float f32x4 __attribute__((ext_vector_type(4)));

#define Bn 8
#define Cdim 256
#define Nn 2304
#define NH 4
#define DH 32
#define HID 128
#define QSCALE (0.17677669529663687f * 1.4426950408889634f)
#define SMAX 14.0f
#define QSZ ((size_t)32 * Nn * DH)
#define WQ_ELEMS (3 * HID * Cdim)
#define WO_ELEMS (Cdim * HID)

// ---------------- Kernel 0: weight cvt + FRAG-MAJOR repack (gather) ----------
__global__ __launch_bounds__(256) void cvt_kernel(const float* __restrict__ wq,
                                                  const float* __restrict__ wo,
                                                  bf16* __restrict__ dst) {
    int d = blockIdx.x * 256 + threadIdx.x;
    {   // wq: 24 o-tiles, 8 kc
        int j = d & 7, lane = (d >> 3) & 63, kc = (d >> 9) & 7, ot = d >> 12;
        int o = ot * 16 + (lane & 15), c = kc * 32 + (lane >> 4) * 8 + j;
        dst[d] = (bf16)wq[o * Cdim + c];
    }
    if (d < WO_ELEMS) {   // wo: 16 o-tiles, 4 kc
        int j = d & 7, lane = (d >> 3) & 63, kc = (d >> 9) & 3, ot = d >> 11;
        int o = ot * 16 + (lane & 15), c = kc * 32 + (lane >> 4) * 8 + j;
        dst[WQ_ELEMS + d] = (bf16)wo[o * HID + c];
    }
}

// ---------------- Kernel 1: QKV projection (LDS-staged x, 4-way o-split) -----
__global__ __launch_bounds__(256) void qkv_kernel(const float* __restrict__ x,
                                                  const bf16* __restrict__ w,
                                                  bf16* __restrict__ ws) {
    __shared__ alignas(16) float xs[256 * 16];   // [ch][px] 16 KB
    const int b   = blockIdx.y;
    const int tid = threadIdx.x;
    const int lane = tid & 63, w4 = tid >> 6, l16 = lane & 15, quad = lane >> 4;
    const int p0  = blockIdx.x * 16;
    const float* xb = x + (size_t)b * Cdim * Nn + p0;

    // stage: wave w4 covers channels [w4*64, +64); lane covers 1 ch x 4 px
    #pragma unroll
    for (int k = 0; k < 4; ++k) {
        const int ch = w4 * 64 + k * 16 + (lane >> 2);
        const int px = (lane & 3) * 4;
        const float4 v = *(const float4*)&xb[(size_t)ch * Nn + px];
        *(float4*)&xs[ch * 16 + px] = v;
    }
    __syncthreads();

    bf16x8 bx[8];
    #pragma unroll
    for (int kc = 0; kc < 8; ++kc)
        #pragma unroll
        for (int jj = 0; jj < 8; ++jj)
            bx[kc][jj] = (bf16)xs[(kc * 32 + quad * 8 + jj) * 16 + l16];

    const int p = p0 + l16;
    #pragma unroll 1
    for (int oi = 0; oi < 6; ++oi) {
        const int ot = w4 * 6 + oi;
        f32x4 acc0 = {0.f, 0.f, 0.f, 0.f};
        f32x4 acc1 = {0.f, 0.f, 0.f, 0.f};
        #pragma unroll
        for (int kc = 0; kc < 4; ++kc) {
            bf16x8 aw0 = *(const bf16x8*)&w[(((size_t)ot * 8 + kc) * 64 + lane) * 8];
            bf16x8 aw1 = *(const bf16x8*)&w[(((size_t)ot * 8 + kc + 4) * 64 + lane) * 8];
            acc0 = __builtin_amdgcn_mfma_f32_16x16x32_bf16(aw0, bx[kc],     acc0, 0, 0, 0);
            acc1 = __builtin_amdgcn_mfma_f32_16x16x32_bf16(aw1, bx[kc + 4], acc1, 0, 0, 0);
        }
        const int obase = ot * 16 + quad * 4;
        const int t     = obase >> 7;
        const int rem   = obase & 127;
        const int h     = rem >> 5;
        const int dbase = rem & 31;
        if (t == 2) {
            // V frag-major: elem (d, n=p) at (n>>5)*1024 + (d>>4)*512
            //   + ((n>>3)&3)*128 + (d&15)*8 + (n&7)
            bf16* vf = ws + 2 * QSZ + (size_t)(b * NH + h) * DH * Nn;
            const int vb_ = (p >> 5) * 1024 + ((p >> 3) & 3) * 128 + (p & 7);
            #pragma unroll
            for (int r = 0; r < 4; ++r) {
                const int d = dbase + r;
                vf[vb_ + (d >> 4) * 512 + (d & 15) * 8] = (bf16)(acc0[r] + acc1[r]);
            }
        } else if (t == 1) {
            bf16x4 v4;
            #pragma unroll
            for (int r = 0; r < 4; ++r) v4[r] = (bf16)(acc0[r] + acc1[r]);
            bf16* kf = ws + QSZ + (size_t)(b * NH + h) * Nn * DH;
            const int pp   = p & 31;
            const int tt   = (pp >> 2) & 1;
            const int rho  = ((pp >> 3) << 2) | (pp & 3);
            const int addr = (((p >> 5) * 2 + tt) * 64 + (dbase >> 3) * 16 + rho) * 8 + (dbase & 7);
            *(bf16x4*)&kf[addr] = v4;
        } else {
            bf16x4 v4;
            #pragma unroll
            for (int r = 0; r < 4; ++r) v4[r] = (bf16)((acc0[r] + acc1[r]) * QSCALE);
            size_t addr = ((size_t)(b * NH + h) * Nn + p) * DH + dbase;
            *(bf16x4*)&ws[addr] = v4;
        }
    }
}

// ---------------- Kernel 2: flash attention (round-3 body, frag-major Ab) ----
// 64 Q-rows/WG, wave w owns j-quarter; reg-P via permuted-K; K AND V register
// double-buffered, prefetch pinned with sched_barrier. launch_bounds(256,2):
// REGISTER-TIER MAP (measured r1/r3/r4/r7): (256,4)=128 cap -> 224B/thread
// spill, 83us; (256,3)=168 cap -> either 64-VGPR squeeze (47us) or in-loop
// spill (137-162us, WRITE 344MB); (256,2) -> no spill, ~38-40us. The 256-VGPR
// tier is the ONLY viable one for this body; do not lower launch_bounds.
// l via ones-MFMA. Combine writes Ab FRAG-MAJOR for coalesced out_kernel reads.
__global__ __launch_bounds__(256, 2) void attn_kernel(bf16* __restrict__ ws) {
    __shared__ alignas(16) float smem[4 * 64 * 17 + 4 * 64];   // 18432 B
    const int g   = blockIdx.x;
    const int grp = g >> 3;
    const int bh  = (g & 7) * 4 + grp / 36;
    const int i0  = (grp % 36) * 64;
    const int tid = threadIdx.x;
    const int lane = tid & 63, w4 = tid >> 6, l16 = lane & 15, quad = lane >> 4;
    const int jbase = w4 * 576;

    const bf16* Qb = ws + (size_t)bh * Nn * DH;
    const bf16* Kf = ws + QSZ + (size_t)bh * Nn * DH;       // permuted frag-major
    const bf16* Vf = ws + 2 * QSZ + (size_t)bh * DH * Nn;   // frag-major A-operand

    bf16x8 aq[4];
    #pragma unroll
    for (int it = 0; it < 4; ++it)
        aq[it] = *(const bf16x8*)&Qb[(size_t)(i0 + it * 16 + l16) * DH + quad * 8];

    f32x4 o[4][2];
    f32x4 la[4];
    #pragma unroll
    for (int it = 0; it < 4; ++it) {
        o[it][0] = {0.f, 0.f, 0.f, 0.f};
        o[it][1] = {0.f, 0.f, 0.f, 0.f};
        la[it]   = {0.f, 0.f, 0.f, 0.f};
    }
    const f32x4 negM = {-SMAX, -SMAX, -SMAX, -SMAX};
    bf16x8 ones;
    #pragma unroll
    for (int j = 0; j < 8; ++j) ones[j] = (bf16)1.0f;

    bf16x8 ka[4], kb[4], va[4], vb[4];
    {   // prologue: cc = 0 into ka/va
        const bf16* kp = &Kf[(size_t)(jbase >> 4) * 512 + lane * 8];
        #pragma unroll
        for (int jt = 0; jt < 4; ++jt) ka[jt] = *(const bf16x8*)&kp[jt * 512];
        const bf16* vp = &Vf[(size_t)(jbase >> 5) * 1024 + lane * 8];
        va[0] = *(const bf16x8*)&vp[0];
        va[1] = *(const bf16x8*)&vp[1024];
        va[2] = *(const bf16x8*)&vp[512];
        va[3] = *(const bf16x8*)&vp[1536];
    }

    auto body = [&](int cc, const bf16x8 (&kc)[4], const bf16x8 (&vc)[4],
                    bf16x8 (&kn)[4], bf16x8 (&vn)[4], bool pref) {
        if (pref) {   // issue next-cc K and V loads FIRST: it-loop covers them
            const int j1 = jbase + cc * 64 + 64;
            const bf16* kp = &Kf[(size_t)(j1 >> 4) * 512 + lane * 8];
            #pragma unroll
            for (int jt = 0; jt < 4; ++jt) kn[jt] = *(const bf16x8*)&kp[jt * 512];
            const bf16* vp = &Vf[(size_t)(j1 >> 5) * 1024 + lane * 8];
            vn[0] = *(const bf16x8*)&vp[0];
            vn[1] = *(const bf16x8*)&vp[1024];
            vn[2] = *(const bf16x8*)&vp[512];
            vn[3] = *(const bf16x8*)&vp[1536];
            __builtin_amdgcn_sched_barrier(0);   // pin: do not sink prefetch
        }
        #pragma unroll
        for (int it = 0; it < 4; ++it) {
            f32x4 s0 = __builtin_amdgcn_mfma_f32_16x16x32_bf16(kc[0], aq[it], negM, 0, 0, 0);
            f32x4 s1 = __builtin_amdgcn_mfma_f32_16x16x32_bf16(kc[1], aq[it], negM, 0, 0, 0);
            f32x4 s2 = __builtin_amdgcn_mfma_f32_16x16x32_bf16(kc[2], aq[it], negM, 0, 0, 0);
            f32x4 s3 = __builtin_amdgcn_mfma_f32_16x16x32_bf16(kc[3], aq[it], negM, 0, 0, 0);
            bf16x8 pf0, pf1;
            #pragma unroll
            for (int r = 0; r < 4; ++r) {
                pf0[r]     = (bf16)__builtin_amdgcn_exp2f(s0[r]);
                pf0[4 + r] = (bf16)__builtin_amdgcn_exp2f(s1[r]);
                pf1[r]     = (bf16)__builtin_amdgcn_exp2f(s2[r]);
                pf1[4 + r] = (bf16)__builtin_amdgcn_exp2f(s3[r]);
            }
            la[it]   = __builtin_amdgcn_mfma_f32_16x16x32_bf16(ones, pf0, la[it], 0, 0, 0);
            la[it]   = __builtin_amdgcn_mfma_f32_16x16x32_bf16(ones, pf1, la[it], 0, 0, 0);
            o[it][0] = __builtin_amdgcn_mfma_f32_16x16x32_bf16(vc[0], pf0, o[it][0], 0, 0, 0);
            o[it][0] = __builtin_amdgcn_mfma_f32_16x16x32_bf16(vc[1], pf1, o[it][0], 0, 0, 0);
            o[it][1] = __builtin_amdgcn_mfma_f32_16x16x32_bf16(vc[2], pf0, o[it][1], 0, 0, 0);
            o[it][1] = __builtin_amdgcn_mfma_f32_16x16x32_bf16(vc[3], pf1, o[it][1], 0, 0, 0);
        }
    };

    #pragma unroll 1
    for (int cp = 0; cp < 4; ++cp) {
        body(cp * 2,     ka, va, kb, vb, true);
        body(cp * 2 + 1, kb, vb, ka, va, true);
    }
    body(8, ka, va, kb, vb, false);

    // ---- split-K combine across the 4 waves, two d-halves over one buffer ----
    // lane holds O^T[d = half*16 + quad*4 + r][i = l16]; la[it][*] = l for i=l16.
    float* ob = smem;                    // [w][64 rows(i)][17]
    float* lb = smem + 4 * 64 * 17;      // [w][64]
    bf16* Ab = ws + 3 * QSZ + (size_t)(bh >> 2) * ((size_t)Nn * HID);  // frag-major per b
    const int hh = bh & 3;

    #pragma unroll
    for (int it = 0; it < 4; ++it) {
        #pragma unroll
        for (int r = 0; r < 4; ++r)
            ob[(w4 * 64 + it * 16 + l16) * 17 + quad * 4 + r] = o[it][0][r];
        if (quad == 0) lb[w4 * 64 + it * 16 + l16] = la[it][0];
    }
    __syncthreads();
    float linv[4];
    #pragma unroll
    for (int k = 0; k < 4; ++k) {
        const int idx = k * 256 + tid;
        const int row = idx >> 4, dd = idx & 15;
        float os = ob[row * 17 + dd] + ob[(64 + row) * 17 + dd]
                 + ob[(128 + row) * 17 + dd] + ob[(192 + row) * 17 + dd];
        float lsum = lb[row] + lb[64 + row] + lb[128 + row] + lb[192 + row];
        linv[k] = 1.0f / lsum;
        const int p = i0 + row;
        Ab[(((size_t)(p >> 4)) * 4 + hh) * 512 + (dd >> 3) * 128 + (p & 15) * 8 + (dd & 7)]
            = (bf16)(os * linv[k]);
    }
    __syncthreads();
    #pragma unroll
    for (int it = 0; it < 4; ++it)
        #pragma unroll
        for (int r = 0; r < 4; ++r)
            ob[(w4 * 64 + it * 16 + l16) * 17 + quad * 4 + r] = o[it][1][r];
    __syncthreads();
    #pragma unroll
    for (int k = 0; k < 4; ++k) {
        const int idx = k * 256 + tid;
        const int row = idx >> 4, dd = idx & 15;
        float os = ob[row * 17 + dd] + ob[(64 + row) * 17 + dd]
                 + ob[(128 + row) * 17 + dd] + ob[(192 + row) * 17 + dd];
        const int p = i0 + row;
        Ab[(((size_t)(p >> 4)) * 4 + hh) * 512 + (2 + (dd >> 3)) * 128 + (p & 15) * 8 + (dd & 7)]
            = (bf16)(os * linv[k]);
    }
}

// ---------------- Kernel 3: output projection (z-split x4, coalesced A) ------
__global__ __launch_bounds__(256) void out_kernel(const bf16* __restrict__ wout,
                                                  const float* __restrict__ bout,
                                                  const bf16* __restrict__ Abuf,
                                                  float* __restrict__ out) {
    const int p0  = blockIdx.x * 64;
    const int b   = blockIdx.y;
    const int otb = blockIdx.z * 4;
    const int tid = threadIdx.x;
    const int lane = tid & 63, w4 = tid >> 6, l16 = lane & 15, quad = lane >> 4;
    const int p = p0 + w4 * 16 + l16;
    const int tile = blockIdx.x * 4 + w4;

    bf16x8 bfrag[4];
    #pragma unroll
    for (int h = 0; h < NH; ++h)
        bfrag[h] = *(const bf16x8*)&Abuf[(((size_t)b * 144 + tile) * 4 + h) * 512 + lane * 8];

    #pragma unroll 1
    for (int oi = 0; oi < 4; ++oi) {
        const int ot = otb + oi;
        const int o0 = ot * 16;
        float4 b4 = *(const float4*)&bout[o0 + quad * 4];
        f32x4 acc0 = {b4.x, b4.y, b4.z, b4.w};
        f32x4 acc1 = {0.f, 0.f, 0.f, 0.f};
        #pragma unroll
        for (int kc = 0; kc < 2; ++kc) {
            bf16x8 aw0 = *(const bf16x8*)&wout[(((size_t)ot * 4 + kc) * 64 + lane) * 8];
            bf16x8 aw1 = *(const bf16x8*)&wout[(((size_t)ot * 4 + kc + 2) * 64 + lane) * 8];
            acc0 = __builtin_amdgcn_mfma_f32_16x16x32_bf16(aw0, bfrag[kc],     acc0, 0, 0, 0);
            acc1 = __builtin_amdgcn_mfma_f32_16x16x32_bf16(aw1, bfrag[kc + 2], acc1, 0, 0, 0);
        }
        #pragma unroll
        for (int r = 0; r < 4; ++r) {
            const int o = o0 + quad * 4 + r;
            out[((size_t)(b * Cdim + o)) * Nn + p] = acc0[r] + acc1[r];
        }
    }
}

extern "C" void kernel_launch(void* const* d_in, const int* in_sizes, int n_in,
                              void* d_out, int out_size, void* d_ws, size_t ws_size,
                              hipStream_t stream) {
    const float* x     = (const float*)d_in[0];
    const float* w_qkv = (const float*)d_in[1];
    const float* w_out = (const float*)d_in[2];
    const float* b_out = (const float*)d_in[3];
    bf16* ws   = (bf16*)d_ws;
    float* out = (float*)d_out;

    bf16* wq_bf = ws + 4 * QSZ;
    bf16* wo_bf = wq_bf + WQ_ELEMS;

    cvt_kernel <<<dim3(WQ_ELEMS / 256), 256, 0, stream>>>(w_qkv, w_out, wq_bf);
    qkv_kernel <<<dim3(144, Bn),   256, 0, stream>>>(x, wq_bf, ws);
    attn_kernel<<<dim3(1152),      256, 0, stream>>>(ws);
    out_kernel <<<dim3(36, Bn, 4), 256, 0, stream>>>(wo_bf, b_out, ws + 3 * QSZ, out);
}